// Round 2
// baseline (262.349 us; speedup 1.0000x reference)
//
#include <hip/hip_runtime.h>

#define IMG 512
#define ROWS 8              // output rows per block
#define NITER 18            // ROWS + 10 input rows
#define NPLANES 24          // N*C = 8*3
#define TOTAL_PIX 6291456.0f
#define NBLOCKS (64 * 24)   // (512/ROWS) * NPLANES

// Gaussian window, sigma=1.5, K=11, normalized (validated: absmax 0.0 in R1)
__device__ __constant__ float GW[11] = {
    0.00102838f, 0.00759876f, 0.03600050f, 0.10935817f, 0.21300535f,
    0.26601172f, 0.21300535f, 0.10935817f, 0.03600050f, 0.00759876f,
    0.00102838f};

// LDS: 5 quantities x 2 buffers x 264 float2 (3 front pads + 256 + 5 back pads)
// vbuf[q*528 + sel*264 + 3 + t] holds cols (2t, 2t+1) of quantity q.
#define VSTRIDE 264
#define QSTRIDE 528
#define LDS_F2 2640

extern "C" __global__ __launch_bounds__(256, 5) void ssim_structure_kernel(
    const float* __restrict__ x, const float* __restrict__ y,
    float* __restrict__ partial) {
  const int tid = threadIdx.x;
  const int chunk = blockIdx.x;  // 0..63 (row chunk)
  const int plane = blockIdx.y;  // 0..23
  const int r0 = chunk * ROWS;

  const size_t pbase = (size_t)plane * (IMG * IMG / 2);  // in float2 units
  const float2* __restrict__ xp = (const float2*)x + pbase;
  const float2* __restrict__ yp = (const float2*)y + pbase;

  __shared__ float2 vbuf[LDS_F2];
  // zero everything once: interior gets overwritten every row, pads stay 0
  // (image-edge zero padding for the horizontal conv falls out of this)
  for (int j = tid; j < LDS_F2; j += 256) vbuf[j] = make_float2(0.f, 0.f);
  __syncthreads();

  // raw circular buffer: 11 rows x (x0,x1,y0,y1) for this thread's 2 columns
  float bx0[11], bx1[11], by0[11], by1[11];
  float acc = 0.0f;

  float2 px, py;
  auto loadrow = [&](int i, float2& ox, float2& oy) {
    const int ir = r0 - 5 + i;
    if (i < NITER && ir >= 0 && ir < IMG) {
      const size_t off = (size_t)ir * (IMG / 2) + tid;
      ox = xp[off];
      oy = yp[off];
    } else {
      ox = make_float2(0.f, 0.f);
      oy = make_float2(0.f, 0.f);
    }
  };
  loadrow(0, px, py);

  for (int ob = 0; ob < 2; ++ob) {
#pragma unroll
    for (int ii = 0; ii < 11; ++ii) {
      const int i = ob * 11 + ii;
      if (i >= NITER) continue;  // uniform guard (4 dead tail iterations)

      // commit prefetched row into circular slot ii (== i % 11)
      bx0[ii] = px.x;
      bx1[ii] = px.y;
      by0[ii] = py.x;
      by1[ii] = py.y;
      // prefetch next row (hide global latency behind compute)
      loadrow(i + 1, px, py);

      if (i >= 10) {
        const int sel = i & 1;
        // ---- vertical 11-tap conv for this thread's 2 columns ----
        float Vx0 = 0.f, Vx1 = 0.f, Vy0 = 0.f, Vy1 = 0.f;
        float Vxx0 = 0.f, Vxx1 = 0.f, Vyy0 = 0.f, Vyy1 = 0.f;
        float Vxy0 = 0.f, Vxy1 = 0.f;
#pragma unroll
        for (int k = 0; k < 11; ++k) {
          const int s = (ii + 1 + k) % 11;  // compile-time after unroll
          const float wgt = GW[k];
          const float wx0 = wgt * bx0[s], wx1 = wgt * bx1[s];
          const float wy0 = wgt * by0[s], wy1 = wgt * by1[s];
          Vx0 += wx0;
          Vx1 += wx1;
          Vy0 += wy0;
          Vy1 += wy1;
          Vxx0 = fmaf(wx0, bx0[s], Vxx0);
          Vxx1 = fmaf(wx1, bx1[s], Vxx1);
          Vxy0 = fmaf(wx0, by0[s], Vxy0);
          Vxy1 = fmaf(wx1, by1[s], Vxy1);
          Vyy0 = fmaf(wy0, by0[s], Vyy0);
          Vyy1 = fmaf(wy1, by1[s], Vyy1);
        }
        // stage vertical sums (cols 2t,2t+1) into LDS
        const int wbase = sel * VSTRIDE + 3 + tid;
        vbuf[0 * QSTRIDE + wbase] = make_float2(Vx0, Vx1);
        vbuf[1 * QSTRIDE + wbase] = make_float2(Vy0, Vy1);
        vbuf[2 * QSTRIDE + wbase] = make_float2(Vxx0, Vxx1);
        vbuf[3 * QSTRIDE + wbase] = make_float2(Vyy0, Vyy1);
        vbuf[4 * QSTRIDE + wbase] = make_float2(Vxy0, Vxy1);
        __syncthreads();

        // ---- horizontal 11-tap conv over vertical sums, 2 output cols ----
        float S0[5], S1[5];
#pragma unroll
        for (int q = 0; q < 5; ++q) {
          const float2* arr = vbuf + q * QSTRIDE + sel * VSTRIDE + tid;
          float a[14];  // cols 2t-6 .. 2t+7 (pads supply image-edge zeros)
#pragma unroll
          for (int d = 0; d < 7; ++d) {
            const float2 v = arr[d];
            a[2 * d] = v.x;
            a[2 * d + 1] = v.y;
          }
          float s0 = 0.f, s1 = 0.f;
#pragma unroll
          for (int d = 0; d < 11; ++d) {
            s0 = fmaf(GW[d], a[d + 1], s0);  // out col 2t:   taps 2t-5..2t+5
            s1 = fmaf(GW[d], a[d + 2], s1);  // out col 2t+1: taps 2t-4..2t+6
          }
          S0[q] = s0;
          S1[q] = s1;
        }
        // ---- epilogue, 2 columns ----
        {
          const float mx = S0[0], my = S0[1];
          const float sxy = fmaf(-mx, my, S0[4]);
          const float sxx = fmaxf(fmaf(-mx, mx, S0[2]), 1e-12f);
          const float syy = fmaxf(fmaf(-my, my, S0[3]), 1e-12f);
          const float den = __builtin_amdgcn_sqrtf(sxx * syy) + 1e-4f;
          acc += (sxy + 1e-4f) * __builtin_amdgcn_rcpf(den);
        }
        {
          const float mx = S1[0], my = S1[1];
          const float sxy = fmaf(-mx, my, S1[4]);
          const float sxx = fmaxf(fmaf(-mx, mx, S1[2]), 1e-12f);
          const float syy = fmaxf(fmaf(-my, my, S1[3]), 1e-12f);
          const float den = __builtin_amdgcn_sqrtf(sxx * syy) + 1e-4f;
          acc += (sxy + 1e-4f) * __builtin_amdgcn_rcpf(den);
        }
      }
    }
  }

  // ---- block reduction: wave shuffle then cross-wave LDS ----
#pragma unroll
  for (int off = 32; off > 0; off >>= 1) acc += __shfl_down(acc, off, 64);
  __shared__ float wsum[4];
  if ((tid & 63) == 0) wsum[tid >> 6] = acc;
  __syncthreads();
  if (tid == 0) {
    partial[blockIdx.y * 64 + blockIdx.x] = wsum[0] + wsum[1] + wsum[2] + wsum[3];
  }
}

extern "C" __global__ void ssim_finalize_kernel(const float* __restrict__ partial,
                                                float* __restrict__ out) {
  const int tid = threadIdx.x;
  float s = 0.f;
  for (int j = tid; j < NBLOCKS; j += 256) s += partial[j];
#pragma unroll
  for (int off = 32; off > 0; off >>= 1) s += __shfl_down(s, off, 64);
  __shared__ float wsum[4];
  if ((tid & 63) == 0) wsum[tid >> 6] = s;
  __syncthreads();
  if (tid == 0) {
    out[0] = 1.0f - (wsum[0] + wsum[1] + wsum[2] + wsum[3]) * (1.0f / TOTAL_PIX);
  }
}

extern "C" void kernel_launch(void* const* d_in, const int* in_sizes, int n_in,
                              void* d_out, int out_size, void* d_ws,
                              size_t ws_size, hipStream_t stream) {
  const float* x = (const float*)d_in[0];
  const float* y = (const float*)d_in[1];
  float* out = (float*)d_out;
  float* partial = (float*)d_ws;  // 1536 floats, fully overwritten every call

  dim3 grid(IMG / ROWS, NPLANES, 1);  // 64 x 24 = 1536 blocks
  ssim_structure_kernel<<<grid, 256, 0, stream>>>(x, y, partial);
  ssim_finalize_kernel<<<1, 256, 0, stream>>>(partial, out);
}

// Round 3
// 134.579 us; speedup vs baseline: 1.9494x; 1.9494x over previous
//
#include <hip/hip_runtime.h>

#define IMG 512
#define ROWS 8              // output rows per block
#define NITER 18            // ROWS + 10 input rows
#define NPLANES 24          // N*C = 8*3
#define TOTAL_PIX 6291456.0f
#define NBLOCKS (64 * 24)   // (512/ROWS) * NPLANES

// Gaussian window, sigma=1.5, K=11, normalized (validated: absmax 0.0 in R1/R2)
__device__ __constant__ float GW[11] = {
    0.00102838f, 0.00759876f, 0.03600050f, 0.10935817f, 0.21300535f,
    0.26601172f, 0.21300535f, 0.10935817f, 0.03600050f, 0.00759876f,
    0.00102838f};

// LDS: 5 quantities x 2 buffers x 264 float2 (3 front pads + 256 + 5 back pads)
// vbuf[q*528 + sel*264 + 3 + t] holds cols (2t, 2t+1) of quantity q.
#define VSTRIDE 264
#define QSTRIDE 528
#define LDS_F2 2640

extern "C" __global__ __launch_bounds__(256, 4) void ssim_structure_kernel(
    const float* __restrict__ x, const float* __restrict__ y,
    float* __restrict__ partial) {
  const int tid = threadIdx.x;
  const int chunk = blockIdx.x;  // 0..63 (row chunk)
  const int plane = blockIdx.y;  // 0..23
  const int r0 = chunk * ROWS;

  const size_t pbase = (size_t)plane * (IMG * IMG / 2);  // in float2 units
  const float2* __restrict__ xp = (const float2*)x + pbase;
  const float2* __restrict__ yp = (const float2*)y + pbase;

  __shared__ float2 vbuf[LDS_F2];
  // zero once: interior overwritten every row, pads stay 0 (image-edge zeros)
  for (int j = tid; j < LDS_F2; j += 256) vbuf[j] = make_float2(0.f, 0.f);
  __syncthreads();

  // circular register buffer: 11 rows x (x0,x1,y0,y1). ALL indices below are
  // compile-time constants (fully unrolled flat structure) -> guaranteed VGPRs.
  float bx0[11], bx1[11], by0[11], by1[11];
  float acc = 0.0f;

  auto loadrow = [&](int i, float2& ox, float2& oy) {
    const int ir = r0 - 5 + i;                 // i is compile-time at call site
    if (i < NITER && ir >= 0 && ir < IMG) {
      const size_t off = (size_t)ir * (IMG / 2) + tid;
      ox = xp[off];
      oy = yp[off];
    } else {
      ox = make_float2(0.f, 0.f);
      oy = make_float2(0.f, 0.f);
    }
  };

  // ---- prologue: fill slots 0..9 (10 independent row loads, issued together)
#pragma unroll
  for (int i = 0; i < 10; ++i) {
    float2 vx, vy;
    loadrow(i, vx, vy);
    bx0[i] = vx.x;
    bx1[i] = vx.y;
    by0[i] = vy.x;
    by1[i] = vy.y;
  }
  float2 px, py;
  loadrow(10, px, py);

  // ---- main: 8 output rows, everything compile-time ----
#pragma unroll
  for (int j = 0; j < ROWS; ++j) {
    const int slot = (10 + j) % 11;  // literal after unroll
    const int sel = j & 1;
    bx0[slot] = px.x;
    bx1[slot] = px.y;
    by0[slot] = py.x;
    by1[slot] = py.y;
    loadrow(11 + j, px, py);  // prefetch next row (dead at j=7, elided)

    // vertical 11-tap conv for this thread's 2 columns
    float Vx0 = 0.f, Vx1 = 0.f, Vy0 = 0.f, Vy1 = 0.f;
    float Vxx0 = 0.f, Vxx1 = 0.f, Vyy0 = 0.f, Vyy1 = 0.f;
    float Vxy0 = 0.f, Vxy1 = 0.f;
#pragma unroll
    for (int k = 0; k < 11; ++k) {
      const int s = (j + k) % 11;  // literal after unroll
      const float wgt = GW[k];
      const float wx0 = wgt * bx0[s], wx1 = wgt * bx1[s];
      const float wy0 = wgt * by0[s], wy1 = wgt * by1[s];
      Vx0 += wx0;
      Vx1 += wx1;
      Vy0 += wy0;
      Vy1 += wy1;
      Vxx0 = fmaf(wx0, bx0[s], Vxx0);
      Vxx1 = fmaf(wx1, bx1[s], Vxx1);
      Vxy0 = fmaf(wx0, by0[s], Vxy0);
      Vxy1 = fmaf(wx1, by1[s], Vxy1);
      Vyy0 = fmaf(wy0, by0[s], Vyy0);
      Vyy1 = fmaf(wy1, by1[s], Vyy1);
    }
    // stage vertical sums (cols 2t,2t+1) into LDS
    const int wbase = sel * VSTRIDE + 3 + tid;
    vbuf[0 * QSTRIDE + wbase] = make_float2(Vx0, Vx1);
    vbuf[1 * QSTRIDE + wbase] = make_float2(Vy0, Vy1);
    vbuf[2 * QSTRIDE + wbase] = make_float2(Vxx0, Vxx1);
    vbuf[3 * QSTRIDE + wbase] = make_float2(Vyy0, Vyy1);
    vbuf[4 * QSTRIDE + wbase] = make_float2(Vxy0, Vxy1);
    __syncthreads();

    // horizontal 11-tap conv over vertical sums, 2 output cols
    float S0[5], S1[5];
#pragma unroll
    for (int q = 0; q < 5; ++q) {
      const float2* arr = vbuf + q * QSTRIDE + sel * VSTRIDE + tid;
      float a[14];  // cols 2t-6 .. 2t+7 (pads supply image-edge zeros)
#pragma unroll
      for (int d = 0; d < 7; ++d) {
        const float2 v = arr[d];
        a[2 * d] = v.x;
        a[2 * d + 1] = v.y;
      }
      float s0 = 0.f, s1 = 0.f;
#pragma unroll
      for (int d = 0; d < 11; ++d) {
        s0 = fmaf(GW[d], a[d + 1], s0);  // out col 2t:   taps 2t-5..2t+5
        s1 = fmaf(GW[d], a[d + 2], s1);  // out col 2t+1: taps 2t-4..2t+6
      }
      S0[q] = s0;
      S1[q] = s1;
    }
    // epilogue, 2 columns
    {
      const float mx = S0[0], my = S0[1];
      const float sxy = fmaf(-mx, my, S0[4]);
      const float sxx = fmaxf(fmaf(-mx, mx, S0[2]), 1e-12f);
      const float syy = fmaxf(fmaf(-my, my, S0[3]), 1e-12f);
      const float den = __builtin_amdgcn_sqrtf(sxx * syy) + 1e-4f;
      acc += (sxy + 1e-4f) * __builtin_amdgcn_rcpf(den);
    }
    {
      const float mx = S1[0], my = S1[1];
      const float sxy = fmaf(-mx, my, S1[4]);
      const float sxx = fmaxf(fmaf(-mx, mx, S1[2]), 1e-12f);
      const float syy = fmaxf(fmaf(-my, my, S1[3]), 1e-12f);
      const float den = __builtin_amdgcn_sqrtf(sxx * syy) + 1e-4f;
      acc += (sxy + 1e-4f) * __builtin_amdgcn_rcpf(den);
    }
  }

  // ---- block reduction: wave shuffle then cross-wave LDS ----
#pragma unroll
  for (int off = 32; off > 0; off >>= 1) acc += __shfl_down(acc, off, 64);
  __shared__ float wsum[4];
  if ((tid & 63) == 0) wsum[tid >> 6] = acc;
  __syncthreads();
  if (tid == 0) {
    partial[blockIdx.y * 64 + blockIdx.x] = wsum[0] + wsum[1] + wsum[2] + wsum[3];
  }
}

extern "C" __global__ void ssim_finalize_kernel(const float* __restrict__ partial,
                                                float* __restrict__ out) {
  const int tid = threadIdx.x;
  float s = 0.f;
  for (int j = tid; j < NBLOCKS; j += 256) s += partial[j];
#pragma unroll
  for (int off = 32; off > 0; off >>= 1) s += __shfl_down(s, off, 64);
  __shared__ float wsum[4];
  if ((tid & 63) == 0) wsum[tid >> 6] = s;
  __syncthreads();
  if (tid == 0) {
    out[0] = 1.0f - (wsum[0] + wsum[1] + wsum[2] + wsum[3]) * (1.0f / TOTAL_PIX);
  }
}

extern "C" void kernel_launch(void* const* d_in, const int* in_sizes, int n_in,
                              void* d_out, int out_size, void* d_ws,
                              size_t ws_size, hipStream_t stream) {
  const float* x = (const float*)d_in[0];
  const float* y = (const float*)d_in[1];
  float* out = (float*)d_out;
  float* partial = (float*)d_ws;  // 1536 floats, fully overwritten every call

  dim3 grid(IMG / ROWS, NPLANES, 1);  // 64 x 24 = 1536 blocks
  ssim_structure_kernel<<<grid, 256, 0, stream>>>(x, y, partial);
  ssim_finalize_kernel<<<1, 256, 0, stream>>>(partial, out);
}